// Round 4
// baseline (4173.777 us; speedup 1.0000x reference)
//
#include <hip/hip_runtime.h>
#include <hip/hip_fp8.h>

#define NROWS 16384
#define DIMIN 1024
#define DIMH  512
#define MEMN  8192
#define NSPLIT 8
#define CSLOTS 16
#define TAU 0.6f

typedef __attribute__((ext_vector_type(8))) short bf16x8;
typedef __attribute__((ext_vector_type(4))) float f32x4;
typedef __attribute__((ext_vector_type(8))) int i32x8;

__device__ __forceinline__ unsigned short bf16_rne(float x) {
    unsigned u = __builtin_bit_cast(unsigned, x);
    unsigned r = u + 0x7fffu + ((u >> 16) & 1u);
    return (unsigned short)(r >> 16);
}
__device__ __forceinline__ float bf16_to_f(unsigned short h) {
    unsigned u = ((unsigned)h) << 16;
    return __builtin_bit_cast(float, u);
}
__device__ __forceinline__ unsigned char f2e4(float x) {
    __hip_fp8_e4m3 t(x);
    return t.__x;
}
__device__ __forceinline__ float e42f(unsigned char b) {
    __hip_fp8_e4m3 t;
    t.__x = b;
    return (float)t;
}
__device__ __forceinline__ void async_copy16(const void* g, void* l) {
    __builtin_amdgcn_global_load_lds(
        (const __attribute__((address_space(1))) unsigned int*)g,
        (__attribute__((address_space(3))) unsigned int*)l, 16, 0, 0);
}
// XOR-swizzle of the 32-byte k-group within each 128-byte k-block (byte col in [0,512))
__device__ __forceinline__ int swz(int row, int col) {
    return (col & ~127) | ((((col >> 5) & 3) ^ (row & 3)) << 5) | (col & 31);
}
__device__ __forceinline__ i32x8 ld32(const unsigned char* p) {
    int4 a = *(const int4*)p, b = *(const int4*)(p + 16);
    i32x8 r;
    r[0] = a.x; r[1] = a.y; r[2] = a.z; r[3] = a.w;
    r[4] = b.x; r[5] = b.y; r[6] = b.z; r[7] = b.w;
    return r;
}

// ---------- mm[j] = sum memory[j]^2 ; split memory into fp8 hi/lo (swizzled) ----------
__global__ __launch_bounds__(256) void k_sumsq_split(const float* __restrict__ mem,
                                                     float* __restrict__ mm,
                                                     unsigned char* __restrict__ M8h,
                                                     unsigned char* __restrict__ M8l) {
    int wave = threadIdx.x >> 6, lane = threadIdx.x & 63;
    int row = blockIdx.x * 4 + wave;
    const float4* r4 = (const float4*)(mem + (size_t)row * DIMH);
    float4 a = r4[2 * lane], b = r4[2 * lane + 1];
    float x[8] = {a.x, a.y, a.z, a.w, b.x, b.y, b.z, b.w};
    unsigned long long hp = 0ull, lp = 0ull;
    float s = 0.f;
    #pragma unroll
    for (int i = 0; i < 8; ++i) {
        s = fmaf(x[i], x[i], s);
        unsigned char hb = f2e4(x[i]);
        unsigned char lb = f2e4(x[i] - e42f(hb));
        hp |= ((unsigned long long)hb) << (8 * i);
        lp |= ((unsigned long long)lb) << (8 * i);
    }
    #pragma unroll
    for (int off = 32; off; off >>= 1) s += __shfl_xor(s, off, 64);
    int sw = swz(row, lane * 8);
    *(unsigned long long*)(M8h + (size_t)row * DIMH + sw) = hp;
    *(unsigned long long*)(M8l + (size_t)row * DIMH + sw) = lp;
    if (lane == 0) mm[row] = s;
}

// ---------- generic fp32 -> bf16 hi/lo splitter (8 elems/thread) ----------
__global__ __launch_bounds__(256) void k_split(const float* __restrict__ x,
                                               unsigned short* __restrict__ h,
                                               unsigned short* __restrict__ l, int n) {
    int i = (blockIdx.x * 256 + threadIdx.x) * 8;
    if (i >= n) return;
    const float4* xp = (const float4*)(x + i);
    float4 a = xp[0], b = xp[1];
    float v[8] = {a.x, a.y, a.z, a.w, b.x, b.y, b.z, b.w};
    union { unsigned short us[8]; int4 q; } hv, lv;
    #pragma unroll
    for (int j = 0; j < 8; ++j) {
        unsigned short hh = bf16_rne(v[j]);
        hv.us[j] = hh;
        lv.us[j] = bf16_rne(v[j] - bf16_to_f(hh));
    }
    *(int4*)(h + i) = hv.q;
    *(int4*)(l + i) = lv.q;
}

// ---------- p = visual @ Wp^T + b : split-bf16 MFMA; outputs Ph (bf16) + P8h/P8l (fp8, swizzled) ----------
__global__ __launch_bounds__(256, 2) void k_proj_mfma(
        const float* __restrict__ A,
        const unsigned short* __restrict__ Bh, const unsigned short* __restrict__ Bl,
        const float* __restrict__ bias,
        unsigned short* __restrict__ Ph,
        unsigned char* __restrict__ P8h, unsigned char* __restrict__ P8l) {
    __shared__ unsigned short sAh[128 * 32];
    __shared__ unsigned short sAl[128 * 32];
    __shared__ unsigned short sBh[128 * 32];
    __shared__ unsigned short sBl[128 * 32];
    const int t = threadIdx.x, w = t >> 6, l = t & 63;
    const int wm = w >> 1, wn = w & 1, lane16 = l & 15, quad = l >> 4;
    const int bm = blockIdx.x * 128, bn = blockIdx.y * 128;
    const int r0 = t >> 2, k0 = (t & 3) * 8, r1 = (t + 256) >> 2;
    const int lds0 = t * 8, lds1 = t * 8 + 2048;
    const int ar = t >> 1, ak = (t & 1) * 16;

    f32x4 acc[4][4];
    #pragma unroll
    for (int mf = 0; mf < 4; ++mf)
        #pragma unroll
        for (int nf = 0; nf < 4; ++nf) acc[mf][nf] = (f32x4){0.f, 0.f, 0.f, 0.f};

    for (int kc = 0; kc < DIMIN; kc += 32) {
        async_copy16(Bh + (size_t)(bn + r0) * DIMIN + kc + k0, sBh + lds0);
        async_copy16(Bh + (size_t)(bn + r1) * DIMIN + kc + k0, sBh + lds1);
        async_copy16(Bl + (size_t)(bn + r0) * DIMIN + kc + k0, sBl + lds0);
        async_copy16(Bl + (size_t)(bn + r1) * DIMIN + kc + k0, sBl + lds1);
        {
            const float4* ap = (const float4*)(A + (size_t)(bm + ar) * DIMIN + kc + ak);
            float4 v0 = ap[0], v1 = ap[1], v2 = ap[2], v3 = ap[3];
            float x[16] = {v0.x, v0.y, v0.z, v0.w, v1.x, v1.y, v1.z, v1.w,
                           v2.x, v2.y, v2.z, v2.w, v3.x, v3.y, v3.z, v3.w};
            union { unsigned short us[16]; int4 q[2]; } hv, lv;
            #pragma unroll
            for (int j = 0; j < 16; ++j) {
                unsigned short hh = bf16_rne(x[j]);
                hv.us[j] = hh;
                lv.us[j] = bf16_rne(x[j] - bf16_to_f(hh));
            }
            *(int4*)(sAh + ar * 32 + ak) = hv.q[0];
            *(int4*)(sAh + ar * 32 + ak + 8) = hv.q[1];
            *(int4*)(sAl + ar * 32 + ak) = lv.q[0];
            *(int4*)(sAl + ar * 32 + ak + 8) = lv.q[1];
        }
        __syncthreads();
        bf16x8 ah[4], al[4];
        #pragma unroll
        for (int mf = 0; mf < 4; ++mf) {
            int r = wm * 64 + mf * 16 + lane16;
            ah[mf] = *(const bf16x8*)(sAh + r * 32 + quad * 8);
            al[mf] = *(const bf16x8*)(sAl + r * 32 + quad * 8);
        }
        #pragma unroll
        for (int nf = 0; nf < 4; ++nf) {
            int r = wn * 64 + nf * 16 + lane16;
            bf16x8 bh = *(const bf16x8*)(sBh + r * 32 + quad * 8);
            bf16x8 bl = *(const bf16x8*)(sBl + r * 32 + quad * 8);
            #pragma unroll
            for (int mf = 0; mf < 4; ++mf) {
                acc[mf][nf] = __builtin_amdgcn_mfma_f32_16x16x32_bf16(ah[mf], bh, acc[mf][nf], 0, 0, 0);
                acc[mf][nf] = __builtin_amdgcn_mfma_f32_16x16x32_bf16(ah[mf], bl, acc[mf][nf], 0, 0, 0);
                acc[mf][nf] = __builtin_amdgcn_mfma_f32_16x16x32_bf16(al[mf], bh, acc[mf][nf], 0, 0, 0);
            }
        }
        __syncthreads();
    }
    #pragma unroll
    for (int nf = 0; nf < 4; ++nf) {
        int col = bn + wn * 64 + nf * 16 + lane16;
        float bb = bias[col];
        #pragma unroll
        for (int mf = 0; mf < 4; ++mf)
            #pragma unroll
            for (int r = 0; r < 4; ++r) {
                int row = bm + wm * 64 + mf * 16 + quad * 4 + r;
                float o = acc[mf][nf][r] + bb;
                Ph[(size_t)row * DIMH + col] = bf16_rne(o);
                unsigned char h8 = f2e4(o);
                unsigned char l8 = f2e4(o - e42f(h8));
                size_t base = (size_t)row * DIMH;
                int sc = swz(row, col);
                P8h[base + sc] = h8;
                P8l[base + sc] = l8;
            }
    }
}

// ---------- MX-fp8 3-term MFMA argmin with per-slot top-2 (values AND indices) ----------
// 256 thr = 4 waves (2x2 over 128x128 tile), BK=128, 16x16x128 f8f6f4 scaled MFMA
__global__ __launch_bounds__(256, 2) void k_argmin_mfma_fp8(
        const unsigned char* __restrict__ P8h, const unsigned char* __restrict__ P8l,
        const unsigned char* __restrict__ M8h, const unsigned char* __restrict__ M8l,
        const float* __restrict__ mm,
        float* __restrict__ cval, int* __restrict__ cidx,
        float* __restrict__ cv2, int* __restrict__ cidx2) {
    __shared__ unsigned char sAh[128 * 128];
    __shared__ unsigned char sAl[128 * 128];
    __shared__ unsigned char sBh[128 * 128];
    __shared__ unsigned char sBl[128 * 128];
    const int t = threadIdx.x;
    const int w = t >> 6, l = t & 63;
    const int wm = w >> 1, wn = w & 1;
    const int lane16 = l & 15, quad = l >> 4;
    const int bm = blockIdx.x * 128;
    const int split = blockIdx.y;
    const int nbase = split * (MEMN / NSPLIT);

    float bestv[16], bestv2[16];
    int besti[16], besti2[16];
    #pragma unroll
    for (int s = 0; s < 16; ++s) {
        bestv[s] = 3.4e38f; bestv2[s] = 3.4e38f; besti[s] = 0; besti2[s] = 0;
    }

    for (int it = 0; it < (MEMN / NSPLIT) / 128; ++it) {
        const int ntile = nbase + it * 128;
        f32x4 acc[4][4];
        #pragma unroll
        for (int mf = 0; mf < 4; ++mf)
            #pragma unroll
            for (int nf = 0; nf < 4; ++nf) acc[mf][nf] = (f32x4){0.f, 0.f, 0.f, 0.f};

        for (int kc = 0; kc < DIMH; kc += 128) {
            // stage 4 x 16KB; chunk c covers row c>>3, bytes (c&7)*16; LDS linear => wave-linear dest
            #pragma unroll
            for (int j = 0; j < 4; ++j) {
                int c = t + 256 * j;
                int row = c >> 3, kb = (c & 7) * 16, dst = c * 16;
                async_copy16(P8h + (size_t)(bm + row) * DIMH + kc + kb, sAh + dst);
                async_copy16(P8l + (size_t)(bm + row) * DIMH + kc + kb, sAl + dst);
                async_copy16(M8h + (size_t)(ntile + row) * DIMH + kc + kb, sBh + dst);
                async_copy16(M8l + (size_t)(ntile + row) * DIMH + kc + kb, sBl + dst);
            }
            __syncthreads();

            i32x8 ah[4], al[4];
            #pragma unroll
            for (int mf = 0; mf < 4; ++mf) {
                int r = wm * 64 + mf * 16 + lane16;
                int o = r * 128 + ((quad ^ (r & 3)) << 5);
                ah[mf] = ld32(sAh + o);
                al[mf] = ld32(sAl + o);
            }
            #pragma unroll
            for (int nf = 0; nf < 4; ++nf) {
                int rb = wn * 64 + nf * 16 + lane16;
                int ob = rb * 128 + ((quad ^ (rb & 3)) << 5);
                i32x8 bh = ld32(sBh + ob);
                i32x8 bl = ld32(sBl + ob);
                #pragma unroll
                for (int mf = 0; mf < 4; ++mf) {
                    acc[mf][nf] = __builtin_amdgcn_mfma_scale_f32_16x16x128_f8f6f4(
                        ah[mf], bh, acc[mf][nf], 0, 0, 0, 127, 0, 127);
                    acc[mf][nf] = __builtin_amdgcn_mfma_scale_f32_16x16x128_f8f6f4(
                        ah[mf], bl, acc[mf][nf], 0, 0, 0, 127, 0, 127);
                    acc[mf][nf] = __builtin_amdgcn_mfma_scale_f32_16x16x128_f8f6f4(
                        al[mf], bh, acc[mf][nf], 0, 0, 0, 127, 0, 127);
                }
            }
            __syncthreads();
        }
        #pragma unroll
        for (int nf = 0; nf < 4; ++nf) {
            int n = ntile + wn * 64 + nf * 16 + lane16;
            float mmv = mm[n];
            #pragma unroll
            for (int mf = 0; mf < 4; ++mf)
                #pragma unroll
                for (int r = 0; r < 4; ++r) {
                    float s = fmaf(-2.0f, acc[mf][nf][r], mmv);
                    int slot = mf * 4 + r;
                    if (s < bestv[slot]) {
                        bestv2[slot] = bestv[slot]; besti2[slot] = besti[slot];
                        bestv[slot] = s; besti[slot] = n;
                    } else if (s < bestv2[slot]) {
                        bestv2[slot] = s; besti2[slot] = n;
                    }
                }
        }
    }
    // top-2 merge across the 16 column lanes
    #pragma unroll
    for (int off = 1; off < 16; off <<= 1) {
        #pragma unroll
        for (int s = 0; s < 16; ++s) {
            float ov = __shfl_xor(bestv[s], off, 64);
            int   oi = __shfl_xor(besti[s], off, 64);
            float o2 = __shfl_xor(bestv2[s], off, 64);
            int   oi2 = __shfl_xor(besti2[s], off, 64);
            if (ov < bestv[s] || (ov == bestv[s] && oi < besti[s])) {
                if (bestv[s] < o2 || (bestv[s] == o2 && besti[s] < oi2)) {
                    bestv2[s] = bestv[s]; besti2[s] = besti[s];
                } else {
                    bestv2[s] = o2; besti2[s] = oi2;
                }
                bestv[s] = ov; besti[s] = oi;
            } else {
                if (ov < bestv2[s] || (ov == bestv2[s] && oi < besti2[s])) {
                    bestv2[s] = ov; besti2[s] = oi;
                }
            }
        }
    }
    if (lane16 == 0) {
        #pragma unroll
        for (int mf = 0; mf < 4; ++mf)
            #pragma unroll
            for (int r = 0; r < 4; ++r) {
                int row = bm + wm * 64 + mf * 16 + quad * 4 + r;
                int slot = split * 2 + wn;
                size_t o = (size_t)row * CSLOTS + slot;
                cval[o] = bestv[mf * 4 + r];
                cidx[o] = besti[mf * 4 + r];
                cv2[o]  = bestv2[mf * 4 + r];
                cidx2[o] = besti2[mf * 4 + r];
            }
    }
}

// ---------- merge slots -> global best; flag rows with gap < TAU; gather ----------
__global__ __launch_bounds__(256) void k_merge_gather(const float* __restrict__ cval,
                                                      const int* __restrict__ cidx,
                                                      const float* __restrict__ cv2,
                                                      const float* __restrict__ Mem,
                                                      float* __restrict__ out0,
                                                      int* __restrict__ bidx,
                                                      int* __restrict__ count,
                                                      int* __restrict__ list) {
    int wave = threadIdx.x >> 6, lane = threadIdx.x & 63;
    int row = blockIdx.x * 4 + wave;
    float v1 = 3.4e38f, v2 = 3.4e38f;
    int i1 = 0;
    #pragma unroll
    for (int s = 0; s < CSLOTS; ++s) {
        float a1 = cval[(size_t)row * CSLOTS + s];
        float b2 = cv2[(size_t)row * CSLOTS + s];
        int   ai = cidx[(size_t)row * CSLOTS + s];
        if (a1 < v1 || (a1 == v1 && ai < i1)) {
            v2 = fminf(v1, b2);
            v1 = a1; i1 = ai;
        } else {
            v2 = fminf(v2, a1);
        }
    }
    if (lane == 0) {
        bidx[row] = i1;
        if (v2 - v1 < TAU) {
            int pos = atomicAdd(count, 1);
            list[pos] = row;
        }
    }
    const float4* src = (const float4*)(Mem + (size_t)i1 * DIMH);
    float4* dst = (float4*)(out0 + (size_t)row * DIMH);
    dst[lane] = src[lane];
    dst[lane + 64] = src[lane + 64];
}

// ---------- exact fp32 re-decision among the 32 slot candidates ----------
__global__ __launch_bounds__(256) void k_rescan(const float* __restrict__ visual,
                                                const float* __restrict__ Wp,
                                                const float* __restrict__ bp,
                                                const float* __restrict__ Mem,
                                                const float* __restrict__ mm,
                                                const int* __restrict__ count,
                                                const int* __restrict__ list,
                                                const int* __restrict__ cidx,
                                                const int* __restrict__ cidx2,
                                                int* __restrict__ bidx,
                                                float* __restrict__ out0) {
    __shared__ float vrow[DIMIN];
    __shared__ float p[DIMH];
    __shared__ float sv[32];
    __shared__ int   si[32];
    __shared__ int   sbest;
    const int t = threadIdx.x;
    int cnt = *count;
    if (cnt > NROWS) cnt = NROWS;
    for (int f = blockIdx.x; f < cnt; f += gridDim.x) {
        int row = list[f];
        __syncthreads();
        *(float4*)&vrow[t * 4] = *(const float4*)(visual + (size_t)row * DIMIN + t * 4);
        __syncthreads();
        #pragma unroll
        for (int cc = 0; cc < 2; ++cc) {
            int c = t + cc * 256;
            const float* wr = Wp + (size_t)c * DIMIN;
            float a0 = 0.f, a1 = 0.f, a2 = 0.f, a3 = 0.f;
            for (int k = 0; k < DIMIN; k += 16) {
                float4 w0 = *(const float4*)(wr + k);
                float4 w1 = *(const float4*)(wr + k + 4);
                float4 w2 = *(const float4*)(wr + k + 8);
                float4 w3 = *(const float4*)(wr + k + 12);
                float4 x0 = *(const float4*)&vrow[k];
                float4 x1 = *(const float4*)&vrow[k + 4];
                float4 x2 = *(const float4*)&vrow[k + 8];
                float4 x3 = *(const float4*)&vrow[k + 12];
                a0 = fmaf(w0.x, x0.x, fmaf(w0.y, x0.y, fmaf(w0.z, x0.z, fmaf(w0.w, x0.w, a0))));
                a1 = fmaf(w1.x, x1.x, fmaf(w1.y, x1.y, fmaf(w1.z, x1.z, fmaf(w1.w, x1.w, a1))));
                a2 = fmaf(w2.x, x2.x, fmaf(w2.y, x2.y, fmaf(w2.z, x2.z, fmaf(w2.w, x2.w, a2))));
                a3 = fmaf(w3.x, x3.x, fmaf(w3.y, x3.y, fmaf(w3.z, x3.z, fmaf(w3.w, x3.w, a3))));
            }
            p[c] = bp[c] + ((a0 + a1) + (a2 + a3));
        }
        __syncthreads();
        int g = t >> 3, sub = t & 7;
        int cand = (g < 16) ? cidx[(size_t)row * CSLOTS + g]
                            : cidx2[(size_t)row * CSLOTS + (g - 16)];
        const float* mr = Mem + (size_t)cand * DIMH + sub * 64;
        const float* pp = p + sub * 64;
        float d = 0.f;
        for (int k = 0; k < 64; k += 4) {
            float4 mv = *(const float4*)(mr + k);
            float4 pv = *(const float4*)(pp + k);
            d = fmaf(mv.x, pv.x, fmaf(mv.y, pv.y, fmaf(mv.z, pv.z, fmaf(mv.w, pv.w, d))));
        }
        #pragma unroll
        for (int off = 1; off < 8; off <<= 1) d += __shfl_xor(d, off, 64);
        if (sub == 0) {
            sv[g] = fmaf(-2.f, d, mm[cand]);
            si[g] = cand;
        }
        __syncthreads();
        if (t == 0) {
            float bv = sv[0]; int bi = si[0];
            for (int gg = 1; gg < 32; ++gg) {
                float v = sv[gg]; int ii = si[gg];
                if (v < bv || (v == bv && ii < bi)) { bv = v; bi = ii; }
            }
            bidx[row] = bi;
            sbest = bi;
        }
        __syncthreads();
        int best = sbest;
        if (t < 128)
            *(float4*)(out0 + (size_t)row * DIMH + t * 4) =
                *(const float4*)(Mem + (size_t)best * DIMH + t * 4);
    }
}

// ---------- upd = (Ph - mem[bidx]) @ Wu^T + b; out1[bidx] += 0.5*upd ----------
__global__ __launch_bounds__(256, 2) void k_upd_mfma(
        const unsigned short* __restrict__ Ph,
        const float* __restrict__ Mem, const int* __restrict__ bidx,
        const unsigned short* __restrict__ Bh, const unsigned short* __restrict__ Bl,
        const float* __restrict__ bias, float* __restrict__ out1) {
    __shared__ unsigned short sAh[128 * 32];
    __shared__ unsigned short sAl[128 * 32];
    __shared__ unsigned short sBh[128 * 32];
    __shared__ unsigned short sBl[128 * 32];
    __shared__ int ridx[128];
    const int t = threadIdx.x, w = t >> 6, l = t & 63;
    const int wm = w >> 1, wn = w & 1, lane16 = l & 15, quad = l >> 4;
    const int bm = blockIdx.x * 128, bn = blockIdx.y * 128;
    const int r0 = t >> 2, k0 = (t & 3) * 8, r1 = (t + 256) >> 2;
    const int lds0 = t * 8, lds1 = t * 8 + 2048;
    const int ar = t >> 1, ak = (t & 1) * 16;
    if (t < 128) ridx[t] = bidx[bm + t];
    __syncthreads();

    f32x4 acc[4][4];
    #pragma unroll
    for (int mf = 0; mf < 4; ++mf)
        #pragma unroll
        for (int nf = 0; nf < 4; ++nf) acc[mf][nf] = (f32x4){0.f, 0.f, 0.f, 0.f};

    for (int kc = 0; kc < DIMH; kc += 32) {
        async_copy16(Bh + (size_t)(bn + r0) * DIMH + kc + k0, sBh + lds0);
        async_copy16(Bh + (size_t)(bn + r1) * DIMH + kc + k0, sBh + lds1);
        async_copy16(Bl + (size_t)(bn + r0) * DIMH + kc + k0, sBl + lds0);
        async_copy16(Bl + (size_t)(bn + r1) * DIMH + kc + k0, sBl + lds1);
        {
            const unsigned short* ph = Ph + (size_t)(bm + ar) * DIMH + kc + ak;
            union { unsigned short us[16]; int4 q[2]; } hq;
            hq.q[0] = *(const int4*)ph; hq.q[1] = *(const int4*)(ph + 8);
            const float* mrow = Mem + (size_t)ridx[ar] * DIMH + kc + ak;
            float4 m0 = *(const float4*)(mrow), m1 = *(const float4*)(mrow + 4);
            float4 m2 = *(const float4*)(mrow + 8), m3 = *(const float4*)(mrow + 12);
            float mv[16] = {m0.x, m0.y, m0.z, m0.w, m1.x, m1.y, m1.z, m1.w,
                            m2.x, m2.y, m2.z, m2.w, m3.x, m3.y, m3.z, m3.w};
            union { unsigned short us[16]; int4 q[2]; } hv, lv;
            #pragma unroll
            for (int j = 0; j < 16; ++j) {
                float d = bf16_to_f(hq.us[j]) - mv[j];
                unsigned short hh = bf16_rne(d);
                hv.us[j] = hh;
                lv.us[j] = bf16_rne(d - bf16_to_f(hh));
            }
            *(int4*)(sAh + ar * 32 + ak) = hv.q[0];
            *(int4*)(sAh + ar * 32 + ak + 8) = hv.q[1];
            *(int4*)(sAl + ar * 32 + ak) = lv.q[0];
            *(int4*)(sAl + ar * 32 + ak + 8) = lv.q[1];
        }
        __syncthreads();
        bf16x8 ah[4], al[4];
        #pragma unroll
        for (int mf = 0; mf < 4; ++mf) {
            int r = wm * 64 + mf * 16 + lane16;
            ah[mf] = *(const bf16x8*)(sAh + r * 32 + quad * 8);
            al[mf] = *(const bf16x8*)(sAl + r * 32 + quad * 8);
        }
        #pragma unroll
        for (int nf = 0; nf < 4; ++nf) {
            int r = wn * 64 + nf * 16 + lane16;
            bf16x8 bh = *(const bf16x8*)(sBh + r * 32 + quad * 8);
            bf16x8 bl = *(const bf16x8*)(sBl + r * 32 + quad * 8);
            #pragma unroll
            for (int mf = 0; mf < 4; ++mf) {
                acc[mf][nf] = __builtin_amdgcn_mfma_f32_16x16x32_bf16(ah[mf], bh, acc[mf][nf], 0, 0, 0);
                acc[mf][nf] = __builtin_amdgcn_mfma_f32_16x16x32_bf16(ah[mf], bl, acc[mf][nf], 0, 0, 0);
                acc[mf][nf] = __builtin_amdgcn_mfma_f32_16x16x32_bf16(al[mf], bh, acc[mf][nf], 0, 0, 0);
            }
        }
        __syncthreads();
    }
    #pragma unroll
    for (int nf = 0; nf < 4; ++nf) {
        int col = bn + wn * 64 + nf * 16 + lane16;
        float bb = bias[col];
        #pragma unroll
        for (int mf = 0; mf < 4; ++mf)
            #pragma unroll
            for (int r = 0; r < 4; ++r) {
                int rowl = wm * 64 + mf * 16 + quad * 4 + r;
                int tgt = ridx[rowl];
                atomicAdd(out1 + (size_t)tgt * DIMH + col, 0.5f * (acc[mf][nf][r] + bb));
            }
    }
}

extern "C" void kernel_launch(void* const* d_in, const int* in_sizes, int n_in,
                              void* d_out, int out_size, void* d_ws, size_t ws_size,
                              hipStream_t stream) {
    const float* visual = (const float*)d_in[0];
    const float* memory = (const float*)d_in[1];
    const float* W_proj = (const float*)d_in[2];
    const float* b_proj = (const float*)d_in[3];
    const float* W_upd  = (const float*)d_in[4];
    const float* b_upd  = (const float*)d_in[5];
    float* out0 = (float*)d_out;
    float* out1 = out0 + (size_t)NROWS * DIMH;

    char* ws = (char*)d_ws;
    unsigned short* Ph  = (unsigned short*)ws;                     // 16 MB
    unsigned char*  P8h = (unsigned char*)(Ph + (size_t)NROWS * DIMH);   // 8 MB
    unsigned char*  P8l = P8h + (size_t)NROWS * DIMH;              // 8 MB
    unsigned char*  M8h = P8l + (size_t)NROWS * DIMH;              // 4 MB
    unsigned char*  M8l = M8h + (size_t)MEMN * DIMH;               // 4 MB
    unsigned short* Wph = (unsigned short*)(M8l + (size_t)MEMN * DIMH);  // 1 MB
    unsigned short* Wpl = Wph + (size_t)DIMH * DIMIN;              // 1 MB
    unsigned short* Wuh = Wpl + (size_t)DIMH * DIMIN;              // 0.5 MB
    unsigned short* Wul = Wuh + (size_t)DIMH * DIMH;               // 0.5 MB
    float* mm   = (float*)(Wul + (size_t)DIMH * DIMH);
    float* cval = mm + MEMN;
    float* cv2  = cval + (size_t)NROWS * CSLOTS;
    int*   cidx = (int*)(cv2 + (size_t)NROWS * CSLOTS);
    int*   cidx2 = cidx + (size_t)NROWS * CSLOTS;
    int*   bidx = cidx2 + (size_t)NROWS * CSLOTS;
    int*   list = bidx + NROWS;
    int*   count = list + NROWS;

    k_sumsq_split<<<MEMN / 4, 256, 0, stream>>>(memory, mm, M8h, M8l);
    k_split<<<(DIMH * DIMIN) / (8 * 256), 256, 0, stream>>>(W_proj, Wph, Wpl, DIMH * DIMIN);
    k_split<<<(DIMH * DIMH) / (8 * 256), 256, 0, stream>>>(W_upd, Wuh, Wul, DIMH * DIMH);
    k_proj_mfma<<<dim3(NROWS / 128, DIMH / 128), 256, 0, stream>>>(
        visual, Wph, Wpl, b_proj, Ph, P8h, P8l);
    k_argmin_mfma_fp8<<<dim3(NROWS / 128, NSPLIT), 256, 0, stream>>>(
        P8h, P8l, M8h, M8l, mm, cval, cidx, cv2, cidx2);
    hipMemsetAsync(count, 0, 4, stream);
    k_merge_gather<<<NROWS / 4, 256, 0, stream>>>(
        cval, cidx, cv2, memory, out0, bidx, count, list);
    k_rescan<<<1024, 256, 0, stream>>>(
        visual, W_proj, b_proj, memory, mm, count, list, cidx, cidx2, bidx, out0);
    hipMemcpyAsync(out1, memory, (size_t)MEMN * DIMH * 4, hipMemcpyDeviceToDevice, stream);
    k_upd_mfma<<<dim3(NROWS / 128, DIMH / 128), 256, 0, stream>>>(
        Ph, memory, bidx, Wuh, Wul, b_upd, out1);
}